// Round 3
// baseline (354.880 us; speedup 1.0000x reference)
//
#include <hip/hip_runtime.h>
#include <cstdint>

// ---------- sizes ----------
#define BT_ROWS 4096      // B*T
#define DM      1024
#define DFF     2730
#define DFFP    2816      // padded to /128
#define TSEQ    2048

typedef float  f32x4  __attribute__((ext_vector_type(4)));
typedef __bf16 bf16x8 __attribute__((ext_vector_type(8)));

typedef __attribute__((address_space(1))) const unsigned int as1_uint;
typedef __attribute__((address_space(3))) unsigned int       as3_uint;

__device__ __forceinline__ unsigned short f2bf(float f) {
  union { float f; unsigned int u; } v; v.f = f;
  unsigned int u = v.u;
  return (unsigned short)((u + 0x7fffu + ((u >> 16) & 1u)) >> 16);  // RNE
}
__device__ __forceinline__ float bf2f(unsigned int b) {
  union { unsigned int u; float f; } v; v.u = b << 16;
  return v.f;
}

__device__ __forceinline__ void async_cp16(const void* g, void* l) {
  // 16B-wide global->LDS DMA; LDS dest is wave-uniform base + lane*16
  __builtin_amdgcn_global_load_lds((as1_uint*)(uintptr_t)g, (as3_uint*)(uintptr_t)l, 16, 0, 0);
}

// ---------- weight convert (+optional zero pad) ----------
__global__ void cvt_pad_kernel(const float* __restrict__ src, unsigned short* __restrict__ dst,
                               int Rs, int Cs, long total, int Cd) {
  long idx = (long)blockIdx.x * 256 + threadIdx.x;
  if (idx >= total) return;
  int r = (int)(idx / Cd), c = (int)(idx % Cd);
  float v = (r < Rs && c < Cs) ? src[(long)r * Cs + c] : 0.f;
  dst[idx] = f2bf(v);
}

// ---------- RMSNorm (fp32 in -> bf16 out), one block per row ----------
__global__ void rmsnorm_kernel(const float* __restrict__ x, const float* __restrict__ g,
                               unsigned short* __restrict__ out) {
  const int row = blockIdx.x, tid = threadIdx.x;
  const float4 xv = reinterpret_cast<const float4*>(x + (long)row * DM)[tid];
  float ss = xv.x * xv.x + xv.y * xv.y + xv.z * xv.z + xv.w * xv.w;
#pragma unroll
  for (int o = 32; o > 0; o >>= 1) ss += __shfl_xor(ss, o);
  __shared__ float wsum[4];
  if ((tid & 63) == 0) wsum[tid >> 6] = ss;
  __syncthreads();
  const float inv = rsqrtf((wsum[0] + wsum[1] + wsum[2] + wsum[3]) * (1.f / DM) + 1e-5f);
  const float4 gv = reinterpret_cast<const float4*>(g)[tid];
  ushort4 o4;
  o4.x = f2bf(xv.x * inv * gv.x);
  o4.y = f2bf(xv.y * inv * gv.y);
  o4.z = f2bf(xv.z * inv * gv.z);
  o4.w = f2bf(xv.w * inv * gv.w);
  reinterpret_cast<ushort4*>(out + (long)row * DM)[tid] = o4;
}

// ---------- RoPE cos/sin table ----------
__global__ void trig_kernel(const int* __restrict__ pos, float* __restrict__ ct, float* __restrict__ st) {
  int idx = blockIdx.x * 256 + threadIdx.x;
  if (idx >= BT_ROWS * 32) return;
  int r = idx >> 5, i = idx & 31;
  float f = powf(10000.f, -(float)(2 * i) * (1.f / 64.f));
  float ang = (float)pos[r] * f;
  float sv, cv;
  sincosf(ang, &sv, &cv);
  ct[idx] = cv; st[idx] = sv;
}

// ---------- RoPE applied in-place to Q,K halves of QK buf (bf16, ld 2048) ----------
__global__ void rope_kernel(unsigned short* __restrict__ QK,
                            const float* __restrict__ ct, const float* __restrict__ st) {
  int idx = blockIdx.x * 256 + threadIdx.x;  // over 4096*512 (row, head*pair)
  if (idx >= BT_ROWS * 512) return;
  int r = idx >> 9, p = idx & 511;
  int h = p >> 5, i = p & 31;
  float c = ct[r * 32 + i], s = st[r * 32 + i];
  unsigned int* base = reinterpret_cast<unsigned int*>(QK + (long)r * 2048 + h * 64 + 2 * i);
  unsigned int q01 = base[0];
  float x0 = bf2f(q01 & 0xffffu), x1 = bf2f(q01 >> 16);
  base[0] = (unsigned int)f2bf(c * x0 - s * x1) | ((unsigned int)f2bf(s * x0 + c * x1) << 16);
  unsigned int k01 = base[512];  // +1024 shorts = K block
  float y0 = bf2f(k01 & 0xffffu), y1 = bf2f(k01 >> 16);
  base[512] = (unsigned int)f2bf(c * y0 - s * y1) | ((unsigned int)f2bf(s * y0 + c * y1) << 16);
}

// ---------- GEMM: C[M,N] = A[M,K] * B[N,K]^T  (bf16 in, fp32 acc) ----------
// EPI 0: bf16 [row][col] store; EPI 1: fp32 store of acc + resid;
// EPI 2: V-transposed bf16 store -> Vt[((b*16+h)*64+d)][t]  (col=(h,d), row=(b,t))
template <int EPI>
__global__ __launch_bounds__(256) void gemm_bt(
    const unsigned short* __restrict__ A, const unsigned short* __restrict__ B,
    void* __restrict__ C, const float* __restrict__ resid,
    int M, int N, int K, int ldc) {
  __shared__ unsigned short As[128 * 32];
  __shared__ unsigned short Bs[128 * 32];
  const int tid = threadIdx.x;
  const int wid = tid >> 6;
  const int lane = tid & 63;
  const long rowBase = (long)blockIdx.y * 128;
  const long colBase = (long)blockIdx.x * 128;
  const int wm = (wid >> 1) * 64;
  const int wn = (wid & 1) * 64;
  const int l4 = lane >> 2;        // staging: row within 16-row chunk
  const int c8 = (lane & 3) * 8;   // staging: col (8 bf16 = 16B)
  const int fr = lane & 15;        // fragment row
  const int fg = lane >> 4;        // fragment k-group

  const f32x4 z4 = {0.f, 0.f, 0.f, 0.f};
  f32x4 acc[4][4];
#pragma unroll
  for (int m = 0; m < 4; ++m)
#pragma unroll
    for (int n = 0; n < 4; ++n) acc[m][n] = z4;

  const int nkt = K >> 5;
  for (int kt = 0; kt < nkt; ++kt) {
    if (kt) __syncthreads();  // previous compute done before LDS overwrite
    const long kOff = (long)kt * 32 + c8;
#pragma unroll
    for (int c = 0; c < 2; ++c) {
      const int chunk = c * 4 + wid;  // wave-uniform LDS base
      async_cp16(A + (rowBase + chunk * 16 + l4) * K + kOff, &As[chunk * 512]);
      async_cp16(B + (colBase + chunk * 16 + l4) * K + kOff, &Bs[chunk * 512]);
    }
    __syncthreads();  // compiler drains vmcnt(0) before s_barrier -> LDS ready
    bf16x8 af[4], bfr[4];
#pragma unroll
    for (int m = 0; m < 4; ++m)
      af[m] = *reinterpret_cast<const bf16x8*>(&As[(wm + m * 16 + fr) * 32 + fg * 8]);
#pragma unroll
    for (int n = 0; n < 4; ++n)
      bfr[n] = *reinterpret_cast<const bf16x8*>(&Bs[(wn + n * 16 + fr) * 32 + fg * 8]);
#pragma unroll
    for (int m = 0; m < 4; ++m)
#pragma unroll
      for (int n = 0; n < 4; ++n)
        acc[m][n] = __builtin_amdgcn_mfma_f32_16x16x32_bf16(af[m], bfr[n], acc[m][n], 0, 0, 0);
  }

  const int erow = fg * 4;  // C: col = lane&15, row = (lane>>4)*4 + reg
  if (EPI == 0) {
    unsigned short* Cp = (unsigned short*)C;
#pragma unroll
    for (int m = 0; m < 4; ++m) {
      const long r0 = rowBase + wm + m * 16 + erow;
#pragma unroll
      for (int n = 0; n < 4; ++n) {
        const long col = colBase + wn + n * 16 + fr;
#pragma unroll
        for (int r = 0; r < 4; ++r) Cp[(r0 + r) * ldc + col] = f2bf(acc[m][n][r]);
      }
    }
  } else if (EPI == 1) {
    float* Cf = (float*)C;
#pragma unroll
    for (int m = 0; m < 4; ++m) {
      const long r0 = rowBase + wm + m * 16 + erow;
#pragma unroll
      for (int n = 0; n < 4; ++n) {
        const long col = colBase + wn + n * 16 + fr;
#pragma unroll
        for (int r = 0; r < 4; ++r) {
          const long o = (r0 + r) * ldc + col;
          Cf[o] = acc[m][n][r] + resid[o];
        }
      }
    }
  } else {
    // V^T store: row=(b,t), col=(h,d) -> Vt[(b*1024+col)*2048 + t], 4 t's packed
    unsigned short* Cp = (unsigned short*)C;
#pragma unroll
    for (int m = 0; m < 4; ++m) {
      const long r0 = rowBase + wm + m * 16 + erow;
      const long bb = r0 >> 11;
      const int  t0 = (int)(r0 & 2047);
#pragma unroll
      for (int n = 0; n < 4; ++n) {
        const long col = colBase + wn + n * 16 + fr;
        uint2 pk;
        pk.x = (unsigned int)f2bf(acc[m][n][0]) | ((unsigned int)f2bf(acc[m][n][1]) << 16);
        pk.y = (unsigned int)f2bf(acc[m][n][2]) | ((unsigned int)f2bf(acc[m][n][3]) << 16);
        *reinterpret_cast<uint2*>(Cp + (bb * 1024 + col) * 2048 + t0) = pk;
      }
    }
  }
}

// ---------- flash attention, causal, 16 heads x d_k=64 ----------
// S' = K*Q^T (swapped) with permuted K staging so P' lands in the PV B-frag
// layout. Block = 4 waves x 16 q-rows. KVBLK=64, K double-buffered in LDS
// (1 barrier/tile), V^T read directly from global (L2-resident).
#define KSTR 72
__global__ __launch_bounds__(256) void attn_kernel(
    const unsigned short* __restrict__ QK, const unsigned short* __restrict__ Vt,
    unsigned short* __restrict__ O) {
  __shared__ unsigned short Ks[2][64 * KSTR];
  const int bh = blockIdx.x;
  const int b = bh >> 4, h = bh & 15;
  const int tid = threadIdx.x;
  const int wid = tid >> 6, lane = tid & 63;
  const int qblk = 31 - blockIdx.y;              // longest-first dispatch
  const int qbase = qblk * 64 + wid * 16;
  const int fr = lane & 15, g = lane >> 4;
  const long rowb = (long)b * TSEQ;
  const int hoff = h * 64;
  const float C2 = 0.18033688011112042f;         // 0.125 * log2(e)

  // K staging map (per 32-row group, permuted rows)
  const int ki = tid >> 3;                       // 0..31
  const int kcol = (tid & 7) * 8;
  const int kgrow = 8 * ((ki & 15) >> 2) + (ki & 3) + ((ki >> 4) << 2);

  const unsigned short* qrow = QK + (rowb + qbase + fr) * 2048 + hoff + g * 8;
  const bf16x8 qb0 = *reinterpret_cast<const bf16x8*>(qrow);
  const bf16x8 qb1 = *reinterpret_cast<const bf16x8*>(qrow + 32);

  const unsigned short* Kg = QK + rowb * 2048 + 1024 + hoff;
  const unsigned short* Vrow = Vt + ((size_t)bh * 64 + fr) * 2048 + g * 8;

  const f32x4 z4 = {0.f, 0.f, 0.f, 0.f};
  f32x4 acc[4];
#pragma unroll
  for (int d = 0; d < 4; ++d) acc[d] = z4;
  float mrun = -1e30f, lrun = 0.f;
  const int qg = qbase + fr;
  const int nkt = qblk + 1;

  uint4 kr0 = *reinterpret_cast<const uint4*>(Kg + (long)kgrow * 2048 + kcol);
  uint4 kr1 = *reinterpret_cast<const uint4*>(Kg + (long)(32 + kgrow) * 2048 + kcol);

  for (int kt = 0; kt < nkt; ++kt) {
    unsigned short* Kb = Ks[kt & 1];
    *reinterpret_cast<uint4*>(&Kb[ki * KSTR + kcol]) = kr0;
    *reinterpret_cast<uint4*>(&Kb[(32 + ki) * KSTR + kcol]) = kr1;
    __syncthreads();   // writes visible; prev tile's compute (other buf) done
    const int kbase = kt * 64;
    if (kt + 1 < nkt) {
      kr0 = *reinterpret_cast<const uint4*>(Kg + (long)(kbase + 64 + kgrow) * 2048 + kcol);
      kr1 = *reinterpret_cast<const uint4*>(Kg + (long)(kbase + 96 + kgrow) * 2048 + kcol);
    }
    // V fragments straight from global (L2-resident)
    bf16x8 vf[4][2];
#pragma unroll
    for (int db = 0; db < 4; ++db)
#pragma unroll
      for (int ks = 0; ks < 2; ++ks)
        vf[db][ks] = *reinterpret_cast<const bf16x8*>(Vrow + (size_t)db * 16 * 2048 + kbase + ks * 32);

    // QK^T: per 32-k group: rows {fr, 16+fr}, contraction d=64 in 2 halves
    f32x4 s1[2], s2[2];
#pragma unroll
    for (int ks = 0; ks < 2; ++ks) {
      const unsigned short* ra = &Kb[(ks * 32 + fr) * KSTR];
      const unsigned short* rc = &Kb[(ks * 32 + 16 + fr) * KSTR];
      f32x4 t1 = z4, t2 = z4;
      t1 = __builtin_amdgcn_mfma_f32_16x16x32_bf16(*reinterpret_cast<const bf16x8*>(ra + g * 8), qb0, t1, 0, 0, 0);
      t1 = __builtin_amdgcn_mfma_f32_16x16x32_bf16(*reinterpret_cast<const bf16x8*>(ra + 32 + g * 8), qb1, t1, 0, 0, 0);
      t2 = __builtin_amdgcn_mfma_f32_16x16x32_bf16(*reinterpret_cast<const bf16x8*>(rc + g * 8), qb0, t2, 0, 0, 0);
      t2 = __builtin_amdgcn_mfma_f32_16x16x32_bf16(*reinterpret_cast<const bf16x8*>(rc + 32 + g * 8), qb1, t2, 0, 0, 0);
      s1[ks] = t1; s2[ks] = t2;
    }

    // lane's 16 raw scores: k = kbase + ks*32 + 8g + {j | 4+j}
    float sc[16];
    if (kt + 1 < nkt) {  // fully causal-visible tile: no mask
#pragma unroll
      for (int ks = 0; ks < 2; ++ks)
#pragma unroll
        for (int j = 0; j < 4; ++j) {
          sc[ks * 8 + j] = s1[ks][j];
          sc[ks * 8 + 4 + j] = s2[ks][j];
        }
    } else {
      const int kb8 = kbase + 8 * g;
#pragma unroll
      for (int ks = 0; ks < 2; ++ks)
#pragma unroll
        for (int j = 0; j < 4; ++j) {
          sc[ks * 8 + j]     = (kb8 + ks * 32 + j     <= qg) ? s1[ks][j] : -1e30f;
          sc[ks * 8 + 4 + j] = (kb8 + ks * 32 + 4 + j <= qg) ? s2[ks][j] : -1e30f;
        }
    }
    float tmax = sc[0];
#pragma unroll
    for (int j = 1; j < 16; ++j) tmax = fmaxf(tmax, sc[j]);
    tmax = fmaxf(tmax, __shfl_xor(tmax, 16));
    tmax = fmaxf(tmax, __shfl_xor(tmax, 32));
    if (__any(tmax > mrun)) {                    // T13 exact: skip when alpha==1
      const float mnew = fmaxf(mrun, tmax);
      const float alpha = exp2f((mrun - mnew) * C2);
#pragma unroll
      for (int db = 0; db < 4; ++db)
#pragma unroll
        for (int r = 0; r < 4; ++r) acc[db][r] *= alpha;
      lrun *= alpha;
      mrun = mnew;
    }
    const float m2 = mrun * C2;
    union { unsigned short u[16]; bf16x8 v[2]; } pb;
    float psum = 0.f;
#pragma unroll
    for (int j = 0; j < 16; ++j) {
      const float p = exp2f(fmaf(sc[j], C2, -m2));
      psum += p;
      pb.u[j] = f2bf(p);
    }
    psum += __shfl_xor(psum, 16);
    psum += __shfl_xor(psum, 32);
    lrun += psum;

    // PV: acc[db] += V^T-frag * P'-frag  (contraction 2 x 32 k)
#pragma unroll
    for (int db = 0; db < 4; ++db) {
      acc[db] = __builtin_amdgcn_mfma_f32_16x16x32_bf16(vf[db][0], pb.v[0], acc[db], 0, 0, 0);
      acc[db] = __builtin_amdgcn_mfma_f32_16x16x32_bf16(vf[db][1], pb.v[1], acc[db], 0, 0, 0);
    }
  }

  const float inv = 1.f / lrun;
  unsigned short* orow = O + (rowb + qbase + fr) * DM + hoff;
#pragma unroll
  for (int db = 0; db < 4; ++db) {
    uint2 pk;
    pk.x = (unsigned int)f2bf(acc[db][0] * inv) | ((unsigned int)f2bf(acc[db][1] * inv) << 16);
    pk.y = (unsigned int)f2bf(acc[db][2] * inv) | ((unsigned int)f2bf(acc[db][3] * inv) << 16);
    *reinterpret_cast<uint2*>(orow + db * 16 + g * 4) = pk;
  }
}

// ---------- SwiGLU: s = U*sigmoid(U)*G, zero the padded cols ----------
__global__ void swiglu_kernel(const unsigned short* __restrict__ UG, unsigned short* __restrict__ S) {
  int idx = blockIdx.x * 256 + threadIdx.x;  // 4096 * (2816/8)
  if (idx >= BT_ROWS * (DFFP / 8)) return;
  int r = idx / (DFFP / 8);
  int c8 = (idx % (DFFP / 8)) * 8;
  const unsigned short* u8 = UG + (long)r * (2 * DFFP) + c8;
  const uint4 uv = *reinterpret_cast<const uint4*>(u8);
  const uint4 gv = *reinterpret_cast<const uint4*>(u8 + DFFP);
  float uu[8] = {bf2f(uv.x & 0xffffu), bf2f(uv.x >> 16), bf2f(uv.y & 0xffffu), bf2f(uv.y >> 16),
                 bf2f(uv.z & 0xffffu), bf2f(uv.z >> 16), bf2f(uv.w & 0xffffu), bf2f(uv.w >> 16)};
  float gg[8] = {bf2f(gv.x & 0xffffu), bf2f(gv.x >> 16), bf2f(gv.y & 0xffffu), bf2f(gv.y >> 16),
                 bf2f(gv.z & 0xffffu), bf2f(gv.z >> 16), bf2f(gv.w & 0xffffu), bf2f(gv.w >> 16)};
  unsigned short ov[8];
#pragma unroll
  for (int j = 0; j < 8; ++j) {
    float v = (c8 + j < DFF) ? uu[j] * gg[j] / (1.f + __expf(-uu[j])) : 0.f;
    ov[j] = f2bf(v);
  }
  ushort4* dst = reinterpret_cast<ushort4*>(S + (long)r * DFFP + c8);
  dst[0] = make_ushort4(ov[0], ov[1], ov[2], ov[3]);
  dst[1] = make_ushort4(ov[4], ov[5], ov[6], ov[7]);
}

// ---------- workspace layout (123.2 MB, lifetime-reused) ----------
static constexpr size_t OFF_WQKV = 0;          // [3072,1024] bf16
static constexpr size_t OFF_WO   = 6291456;    // [1024,1024] bf16
static constexpr size_t OFF_W13  = 8388608;    // [5632,1024] bf16 (W1 pad | W3 pad)
static constexpr size_t OFF_W2   = 19922944;   // [1024,2816] bf16
static constexpr size_t OFF_H    = 25690112;   // [4096,1024] bf16
static constexpr size_t OFF_X2   = 34078720;   // [4096,1024] f32
static constexpr size_t OFF_CT   = 50855936;   // [4096,32] f32
static constexpr size_t OFF_ST   = 51380224;   // [4096,32] f32
static constexpr size_t OFF_QK   = 51904512;   // [4096,2048] bf16 (later: S [4096,2816])
static constexpr size_t OFF_VT   = 68681728;   // [2048,(b,h,d)][2048 t] bf16, 8MB
static constexpr size_t OFF_HO   = 77070336;   // [4096,1024] bf16 (later: UG [4096,5632])

extern "C" void kernel_launch(void* const* d_in, const int* in_sizes, int n_in,
                              void* d_out, int out_size, void* d_ws, size_t ws_size,
                              hipStream_t stream) {
  const float* x  = (const float*)d_in[0];
  const int* tpos = (const int*)d_in[1];
  const float* WQ = (const float*)d_in[2];
  const float* WK = (const float*)d_in[3];
  const float* WV = (const float*)d_in[4];
  const float* WO = (const float*)d_in[5];
  const float* W1 = (const float*)d_in[6];
  const float* W2 = (const float*)d_in[7];
  const float* W3 = (const float*)d_in[8];
  const float* g1 = (const float*)d_in[9];
  const float* g2 = (const float*)d_in[10];
  float* out = (float*)d_out;

  char* ws = (char*)d_ws;
  unsigned short* Wqkv = (unsigned short*)(ws + OFF_WQKV);
  unsigned short* Wo   = (unsigned short*)(ws + OFF_WO);
  unsigned short* W13  = (unsigned short*)(ws + OFF_W13);
  unsigned short* W2p  = (unsigned short*)(ws + OFF_W2);
  unsigned short* hbuf = (unsigned short*)(ws + OFF_H);
  float* x2            = (float*)(ws + OFF_X2);
  float* ct            = (float*)(ws + OFF_CT);
  float* st            = (float*)(ws + OFF_ST);
  unsigned short* QKb  = (unsigned short*)(ws + OFF_QK);
  unsigned short* Sbuf = (unsigned short*)(ws + OFF_QK);   // reuse after attn
  unsigned short* Vtb  = (unsigned short*)(ws + OFF_VT);
  unsigned short* Ho   = (unsigned short*)(ws + OFF_HO);
  unsigned short* UG   = (unsigned short*)(ws + OFF_HO);   // reuse after O-proj

  // weights -> bf16 (packed, padded)
  auto cvt = [&](const float* s, unsigned short* d, int Rs, int Cs, int Rd, int Cd) {
    long tot = (long)Rd * Cd;
    cvt_pad_kernel<<<(int)((tot + 255) / 256), 256, 0, stream>>>(s, d, Rs, Cs, tot, Cd);
  };
  cvt(WQ, Wqkv,              1024, 1024, 1024, 1024);
  cvt(WK, Wqkv + 1024 * 1024,1024, 1024, 1024, 1024);
  cvt(WV, Wqkv + 2048 * 1024,1024, 1024, 1024, 1024);
  cvt(WO, Wo,                1024, 1024, 1024, 1024);
  cvt(W1, W13,               DFF,  1024, DFFP, 1024);
  cvt(W3, W13 + DFFP * 1024, DFF,  1024, DFFP, 1024);
  cvt(W2, W2p,               1024, DFF,  1024, DFFP);

  // attention sublayer
  rmsnorm_kernel<<<BT_ROWS, 256, 0, stream>>>(x, g1, hbuf);
  trig_kernel<<<(BT_ROWS * 32) / 256, 256, 0, stream>>>(tpos, ct, st);
  gemm_bt<0><<<dim3(16, 32), 256, 0, stream>>>(hbuf, Wqkv, QKb, nullptr, BT_ROWS, 2048, 1024, 2048);
  gemm_bt<2><<<dim3(8, 32), 256, 0, stream>>>(hbuf, Wqkv + 2048 * 1024, Vtb, nullptr, BT_ROWS, 1024, 1024, 2048);
  rope_kernel<<<(BT_ROWS * 512) / 256, 256, 0, stream>>>(QKb, ct, st);
  attn_kernel<<<dim3(32, 32), 256, 0, stream>>>(QKb, Vtb, Ho);
  gemm_bt<1><<<dim3(8, 32), 256, 0, stream>>>(Ho, Wo, x2, x, BT_ROWS, 1024, 1024, 1024);

  // FFN sublayer
  rmsnorm_kernel<<<BT_ROWS, 256, 0, stream>>>(x2, g2, hbuf);
  gemm_bt<0><<<dim3(44, 32), 256, 0, stream>>>(hbuf, W13, UG, nullptr, BT_ROWS, 2 * DFFP, 1024, 2 * DFFP);
  swiglu_kernel<<<(BT_ROWS * (DFFP / 8) + 255) / 256, 256, 0, stream>>>(UG, Sbuf);
  gemm_bt<1><<<dim3(8, 32), 256, 0, stream>>>(Sbuf, W2p, out, x2, BT_ROWS, 1024, DFFP, 1024);
}